// Round 3
// baseline (2489.456 us; speedup 1.0000x reference)
//
// EpisodicMemory: fp32 inputs/output (reference is float32; prior NaNs were from
// misreading fp32 buffers as bf16).
// Structure:
//   g_kernel  : per-b block. feat(64x2048)@fc1_w^T(120x2048) via bf16 MFMA (convert
//               on the fly) -> tanh -> fc2 dot -> sigmoid -> G[b,s] fp32.
//   scan_step : one launch per t (64). gates = C_t@Wih^T + h@Whh^T with FULL hi/lo
//               bf16 split of both operands (3-term MFMA products) -> ~fp32-exact.
//               h carried as bf16 hi+lo pair, double-buffered across steps.
#include <hip/hip_runtime.h>
#include <hip/hip_bf16.h>

#define H_ 512
#define SH_ 120
#define B_ 1024
#define S_ 64

typedef __bf16 bf16x8 __attribute__((ext_vector_type(8)));
typedef float floatx4 __attribute__((ext_vector_type(4)));

__device__ __forceinline__ float bf2f(ushort u) {
    union { unsigned int i; float f; } v; v.i = ((unsigned int)u) << 16; return v.f;
}
__device__ __forceinline__ ushort f2bf(float f) {
    union { float f; unsigned int i; } v; v.f = f;
    unsigned int x = v.i;
    unsigned int r = (x + 0x7fffu + ((x >> 16) & 1u)) >> 16;  // RNE
    return (ushort)r;
}

// ---------------------------------------------------------------------------
// G kernel: one block per b. Computes G[b, s] for s=0..63. fp32 in, fp32 G out.
// ---------------------------------------------------------------------------
__global__ __launch_bounds__(256) void g_kernel(
    const float* __restrict__ C, const float* __restrict__ Q,
    const float* __restrict__ M, const float* __restrict__ fc1w,
    const float* __restrict__ fc1b, const float* __restrict__ fc2w,
    const float* __restrict__ fc2b, float* __restrict__ G)
{
    __shared__ float qrow[H_];
    __shared__ float mrow[H_];
    __shared__ __align__(16) ushort featT[64 * 72];   // 64 s-rows x 64 k (stride 72)
    __shared__ __align__(16) ushort wT[128 * 72];     // 128 n-rows x 64 k (rows>=120 zero)
    __shared__ float h1s[64 * 132];                   // 64 x 128 fp32 (stride 132)

    const int b = blockIdx.x;
    const int t = threadIdx.x;
    for (int i = t; i < H_; i += 256) { qrow[i] = Q[(size_t)b * H_ + i]; mrow[i] = M[(size_t)b * H_ + i]; }
    __syncthreads();

    const int lane = t & 63;
    const int wv   = t >> 6;
    const int quad = lane >> 4;
    const int l15  = lane & 15;
    const int arow = wv * 16 + l15;

    floatx4 acc[8];
#pragma unroll
    for (int i = 0; i < 8; ++i) acc[i] = (floatx4){0.f, 0.f, 0.f, 0.f};

    for (int kc = 0; kc < 4 * H_; kc += 64) {
        const int seg   = kc >> 9;        // 0:C*Q 1:C*M 2:|C-Q| 3:|C-M|
        const int hbase = kc & (H_ - 1);
        // --- feat tile: thread covers row s=t>>2, 16 cols at (t&3)*16 ---
        {
            const int s  = t >> 2;
            const int c0 = (t & 3) * 16;
            const float4* csrc = (const float4*)(C + ((size_t)b * S_ + s) * H_ + hbase + c0);
            float cr[16];
            *(float4*)&cr[0]  = csrc[0];
            *(float4*)&cr[4]  = csrc[1];
            *(float4*)&cr[8]  = csrc[2];
            *(float4*)&cr[12] = csrc[3];
#pragma unroll
            for (int u = 0; u < 16; ++u) {
                const int kk = c0 + u;
                const float c = cr[u];
                const float o = (seg == 0 || seg == 2) ? qrow[hbase + kk] : mrow[hbase + kk];
                const float v = (seg < 2) ? c * o : fabsf(c - o);
                featT[s * 72 + kk] = f2bf(v);
            }
        }
        // --- fc1_w tile: row = t>>1 (0..127), 32 cols at (t&1)*32 ---
        {
            const int row = t >> 1;
            const int c0  = (t & 1) * 32;
            __align__(16) ushort wb[32];
            if (row < SH_) {
                const float4* src = (const float4*)(fc1w + (size_t)row * (4 * H_) + kc + c0);
                float wr[32];
#pragma unroll
                for (int q = 0; q < 8; ++q) *(float4*)&wr[q * 4] = src[q];
#pragma unroll
                for (int u = 0; u < 32; ++u) wb[u] = f2bf(wr[u]);
            } else {
#pragma unroll
                for (int u = 0; u < 32; ++u) wb[u] = 0;
            }
            uint4* dst = (uint4*)&wT[row * 72 + c0];
            dst[0] = ((uint4*)wb)[0]; dst[1] = ((uint4*)wb)[1];
            dst[2] = ((uint4*)wb)[2]; dst[3] = ((uint4*)wb)[3];
        }
        __syncthreads();
#pragma unroll
        for (int ks = 0; ks < 64; ks += 32) {
            const int ao = ks + quad * 8;
            const bf16x8 af = *(const bf16x8*)&featT[arow * 72 + ao];
#pragma unroll
            for (int nt = 0; nt < 8; ++nt) {
                const bf16x8 bfr = *(const bf16x8*)&wT[(nt * 16 + l15) * 72 + ao];
                acc[nt] = __builtin_amdgcn_mfma_f32_16x16x32_bf16(af, bfr, acc[nt], 0, 0, 0);
            }
        }
        __syncthreads();
    }

    // --- epilogue: h1 = tanh(acc + fc1_b) into LDS ---
#pragma unroll
    for (int nt = 0; nt < 8; ++nt) {
        const int col = nt * 16 + l15;
        const float bias = (col < SH_) ? fc1b[col] : 0.f;
#pragma unroll
        for (int r = 0; r < 4; ++r) {
            const int row = wv * 16 + quad * 4 + r;
            h1s[row * 132 + col] = (col < SH_) ? tanhf(acc[nt][r] + bias) : 0.f;
        }
    }
    __syncthreads();
    // --- fc2 + sigmoid: 4 threads per s-row ---
    {
        const int s = t >> 2;
        const int part = t & 3;
        float sum = 0.f;
        for (int k = part; k < SH_; k += 4) sum += h1s[s * 132 + k] * fc2w[k];
        sum += __shfl_xor(sum, 1);
        sum += __shfl_xor(sum, 2);
        if (part == 0) {
            const float logit = sum + fc2b[0];
            G[(size_t)b * S_ + s] = 1.f / (1.f + expf(-logit));
        }
    }
}

// ---------------------------------------------------------------------------
// scan_step: grid = 256 blocks = 16 j-tiles x 16 b-tiles. Block computes h_new
// for its 64-batch x 32-hidden tile at step tstep. hi/lo split of C and W on
// the fly; h state is pre-split (hhi/hlo ws arrays). Double-buffered state.
// ---------------------------------------------------------------------------
__global__ __launch_bounds__(256) void scan_step(
    const float* __restrict__ C, const float* __restrict__ Wih,
    const float* __restrict__ Whh, const float* __restrict__ bih,
    const float* __restrict__ bhh, const float* __restrict__ G,
    const ushort* __restrict__ hhi_r, const ushort* __restrict__ hlo_r,
    ushort* __restrict__ hhi_w, ushort* __restrict__ hlo_w,
    float* __restrict__ out, int tstep, int last)
{
    __shared__ __align__(16) ushort As[4 * 64 * 72];  // c_hi | c_lo | h_hi | h_lo
    __shared__ __align__(16) ushort Bs[4 * 96 * 72];  // Wih_hi | Wih_lo | Whh_hi | Whh_lo

    const int bx = blockIdx.x;
    const int jt = bx & 15;
    const int bt = bx >> 4;
    const int jb = jt * 32;
    const int bb = bt * 64;
    const int t  = threadIdx.x;
    const int lane = t & 63;
    const int wv   = t >> 6;
    const int quad = lane >> 4;
    const int l15  = lane & 15;
    const int arow = wv * 16 + l15;

    floatx4 acc_r[2], acc_z[2], acc_xn[2], acc_hn[2];
#pragma unroll
    for (int i = 0; i < 2; ++i) {
        acc_r[i] = (floatx4){0.f,0.f,0.f,0.f}; acc_z[i]  = (floatx4){0.f,0.f,0.f,0.f};
        acc_xn[i]= (floatx4){0.f,0.f,0.f,0.f}; acc_hn[i] = (floatx4){0.f,0.f,0.f,0.f};
    }

    for (int kc = 0; kc < H_; kc += 64) {
        // --- C tile (fp32 -> hi/lo): row = t>>2, 16 cols at (t&3)*16 ---
        {
            const int row = t >> 2;
            const int c0  = (t & 3) * 16;
            const float4* src = (const float4*)(C + ((size_t)(bb + row) * S_ + tstep) * H_ + kc + c0);
            float cr[16];
            *(float4*)&cr[0]  = src[0];
            *(float4*)&cr[4]  = src[1];
            *(float4*)&cr[8]  = src[2];
            *(float4*)&cr[12] = src[3];
            __align__(16) ushort hi16[16], lo16[16];
#pragma unroll
            for (int u = 0; u < 16; ++u) {
                const ushort h = f2bf(cr[u]);
                hi16[u] = h;
                lo16[u] = f2bf(cr[u] - bf2f(h));
            }
            uint4* dh = (uint4*)&As[0 * 4608 + row * 72 + c0];
            uint4* dl = (uint4*)&As[1 * 4608 + row * 72 + c0];
            dh[0] = ((uint4*)hi16)[0]; dh[1] = ((uint4*)hi16)[1];
            dl[0] = ((uint4*)lo16)[0]; dl[1] = ((uint4*)lo16)[1];
        }
        // --- h tiles (already bf16 hi/lo): 2*64*8 = 1024 uint4, 4 per thread ---
#pragma unroll
        for (int i = 0; i < 4; ++i) {
            const int gid  = i * 256 + t;
            const int tile = gid >> 9;        // 0: h_hi, 1: h_lo
            const int rem  = gid & 511;
            const int row  = rem >> 3;
            const int grp  = rem & 7;
            const ushort* src = (tile ? hlo_r : hhi_r) + (size_t)(bb + row) * H_ + kc + grp * 8;
            *(uint4*)&As[(2 + tile) * 4608 + row * 72 + grp * 8] = *(const uint4*)src;
        }
        // --- W tiles (fp32 -> hi/lo): 2 mats x 96 rows x 8 grps = 1536, 6 per thread ---
#pragma unroll
        for (int i = 0; i < 6; ++i) {
            const int gid = i * 256 + t;
            const int mat = (gid >= 768) ? 1 : 0;
            const int rem = gid - mat * 768;
            const int row = rem >> 3;         // 0..95
            const int grp = rem & 7;
            const int gate = row >> 5;
            const int jj   = row & 31;
            const int grow = gate * H_ + jb + jj;
            const float4* src = (const float4*)((mat == 0 ? Wih : Whh) + (size_t)grow * H_ + kc + grp * 8);
            float wr[8];
            *(float4*)&wr[0] = src[0];
            *(float4*)&wr[4] = src[1];
            __align__(16) ushort hi8[8], lo8[8];
#pragma unroll
            for (int u = 0; u < 8; ++u) {
                const ushort h = f2bf(wr[u]);
                hi8[u] = h;
                lo8[u] = f2bf(wr[u] - bf2f(h));
            }
            *(uint4*)&Bs[(mat * 2 + 0) * 6912 + row * 72 + grp * 8] = *(uint4*)hi8;
            *(uint4*)&Bs[(mat * 2 + 1) * 6912 + row * 72 + grp * 8] = *(uint4*)lo8;
        }
        __syncthreads();
#pragma unroll
        for (int ks = 0; ks < 64; ks += 32) {
            const int ao = ks + quad * 8;
            const bf16x8 a_chi = *(const bf16x8*)&As[0 * 4608 + arow * 72 + ao];
            const bf16x8 a_clo = *(const bf16x8*)&As[1 * 4608 + arow * 72 + ao];
            const bf16x8 a_hhi = *(const bf16x8*)&As[2 * 4608 + arow * 72 + ao];
            const bf16x8 a_hlo = *(const bf16x8*)&As[3 * 4608 + arow * 72 + ao];
#pragma unroll
            for (int nt = 0; nt < 2; ++nt) {
                const int jj = nt * 16 + l15;
                // gate r (0), gate z (1): x-part and h-part both into same acc
                {
                    const int br = (0 * 32 + jj) * 72 + ao;
                    const bf16x8 ih_h = *(const bf16x8*)&Bs[0 * 6912 + br];
                    const bf16x8 ih_l = *(const bf16x8*)&Bs[1 * 6912 + br];
                    const bf16x8 hh_h = *(const bf16x8*)&Bs[2 * 6912 + br];
                    const bf16x8 hh_l = *(const bf16x8*)&Bs[3 * 6912 + br];
                    acc_r[nt] = __builtin_amdgcn_mfma_f32_16x16x32_bf16(a_chi, ih_h, acc_r[nt], 0, 0, 0);
                    acc_r[nt] = __builtin_amdgcn_mfma_f32_16x16x32_bf16(a_chi, ih_l, acc_r[nt], 0, 0, 0);
                    acc_r[nt] = __builtin_amdgcn_mfma_f32_16x16x32_bf16(a_clo, ih_h, acc_r[nt], 0, 0, 0);
                    acc_r[nt] = __builtin_amdgcn_mfma_f32_16x16x32_bf16(a_hhi, hh_h, acc_r[nt], 0, 0, 0);
                    acc_r[nt] = __builtin_amdgcn_mfma_f32_16x16x32_bf16(a_hhi, hh_l, acc_r[nt], 0, 0, 0);
                    acc_r[nt] = __builtin_amdgcn_mfma_f32_16x16x32_bf16(a_hlo, hh_h, acc_r[nt], 0, 0, 0);
                }
                {
                    const int br = (1 * 32 + jj) * 72 + ao;
                    const bf16x8 ih_h = *(const bf16x8*)&Bs[0 * 6912 + br];
                    const bf16x8 ih_l = *(const bf16x8*)&Bs[1 * 6912 + br];
                    const bf16x8 hh_h = *(const bf16x8*)&Bs[2 * 6912 + br];
                    const bf16x8 hh_l = *(const bf16x8*)&Bs[3 * 6912 + br];
                    acc_z[nt] = __builtin_amdgcn_mfma_f32_16x16x32_bf16(a_chi, ih_h, acc_z[nt], 0, 0, 0);
                    acc_z[nt] = __builtin_amdgcn_mfma_f32_16x16x32_bf16(a_chi, ih_l, acc_z[nt], 0, 0, 0);
                    acc_z[nt] = __builtin_amdgcn_mfma_f32_16x16x32_bf16(a_clo, ih_h, acc_z[nt], 0, 0, 0);
                    acc_z[nt] = __builtin_amdgcn_mfma_f32_16x16x32_bf16(a_hhi, hh_h, acc_z[nt], 0, 0, 0);
                    acc_z[nt] = __builtin_amdgcn_mfma_f32_16x16x32_bf16(a_hhi, hh_l, acc_z[nt], 0, 0, 0);
                    acc_z[nt] = __builtin_amdgcn_mfma_f32_16x16x32_bf16(a_hlo, hh_h, acc_z[nt], 0, 0, 0);
                }
                {
                    const int br = (2 * 32 + jj) * 72 + ao;
                    const bf16x8 ih_h = *(const bf16x8*)&Bs[0 * 6912 + br];
                    const bf16x8 ih_l = *(const bf16x8*)&Bs[1 * 6912 + br];
                    const bf16x8 hh_h = *(const bf16x8*)&Bs[2 * 6912 + br];
                    const bf16x8 hh_l = *(const bf16x8*)&Bs[3 * 6912 + br];
                    acc_xn[nt] = __builtin_amdgcn_mfma_f32_16x16x32_bf16(a_chi, ih_h, acc_xn[nt], 0, 0, 0);
                    acc_xn[nt] = __builtin_amdgcn_mfma_f32_16x16x32_bf16(a_chi, ih_l, acc_xn[nt], 0, 0, 0);
                    acc_xn[nt] = __builtin_amdgcn_mfma_f32_16x16x32_bf16(a_clo, ih_h, acc_xn[nt], 0, 0, 0);
                    acc_hn[nt] = __builtin_amdgcn_mfma_f32_16x16x32_bf16(a_hhi, hh_h, acc_hn[nt], 0, 0, 0);
                    acc_hn[nt] = __builtin_amdgcn_mfma_f32_16x16x32_bf16(a_hhi, hh_l, acc_hn[nt], 0, 0, 0);
                    acc_hn[nt] = __builtin_amdgcn_mfma_f32_16x16x32_bf16(a_hlo, hh_h, acc_hn[nt], 0, 0, 0);
                }
            }
        }
        __syncthreads();
    }

    // --- epilogue: gates -> h_new ---
#pragma unroll
    for (int nt = 0; nt < 2; ++nt) {
        const int j = jb + nt * 16 + l15;
        const float br  = bih[j]          + bhh[j];
        const float bz  = bih[H_ + j]     + bhh[H_ + j];
        const float bxn = bih[2 * H_ + j];
        const float bhn = bhh[2 * H_ + j];
#pragma unroll
        for (int r4 = 0; r4 < 4; ++r4) {
            const int b = bb + wv * 16 + quad * 4 + r4;
            const size_t idx = (size_t)b * H_ + j;
            const float hold = bf2f(hhi_r[idx]) + bf2f(hlo_r[idx]);  // read-buffer: no race
            const float g = G[(size_t)b * S_ + tstep];
            const float rg = 1.f / (1.f + expf(-(acc_r[nt][r4] + br)));
            const float zg = 1.f / (1.f + expf(-(acc_z[nt][r4] + bz)));
            const float ng = tanhf(acc_xn[nt][r4] + bxn + rg * (acc_hn[nt][r4] + bhn));
            const float hgru = (1.f - zg) * ng + zg * hold;
            const float hnew = g * hgru + (1.f - g) * hold;
            const ushort hb = f2bf(hnew);
            hhi_w[idx] = hb;
            hlo_w[idx] = f2bf(hnew - bf2f(hb));
            if (last) out[idx] = hnew;
        }
    }
}

extern "C" void kernel_launch(void* const* d_in, const int* in_sizes, int n_in,
                              void* d_out, int out_size, void* d_ws, size_t ws_size,
                              hipStream_t stream) {
    (void)in_sizes; (void)n_in; (void)out_size; (void)ws_size;
    const float* C    = (const float*)d_in[0];
    const float* Q    = (const float*)d_in[1];
    const float* M    = (const float*)d_in[2];
    const float* fc1w = (const float*)d_in[3];
    const float* fc1b = (const float*)d_in[4];
    const float* fc2w = (const float*)d_in[5];
    const float* fc2b = (const float*)d_in[6];
    const float* Wih  = (const float*)d_in[7];
    const float* Whh  = (const float*)d_in[8];
    const float* bih  = (const float*)d_in[9];
    const float* bhh  = (const float*)d_in[10];
    float* out = (float*)d_out;

    char* ws = (char*)d_ws;
    float*  Gbuf = (float*)ws;                         // 256 KB
    ushort* hhi0 = (ushort*)(ws + 262144);             // 1 MB
    ushort* hlo0 = (ushort*)(ws + 262144 + 1048576);   // 1 MB
    ushort* hhi1 = (ushort*)(ws + 262144 + 2097152);   // 1 MB
    ushort* hlo1 = (ushort*)(ws + 262144 + 3145728);   // 1 MB

    // h0 = 0: zero buffer 0 (buffer 1 is fully written at step 0 before step 1 reads it)
    hipMemsetAsync(hhi0, 0, 2097152, stream);

    g_kernel<<<B_, 256, 0, stream>>>(C, Q, M, fc1w, fc1b, fc2w, fc2b, Gbuf);
    for (int t = 0; t < S_; ++t) {
        const ushort* hr_hi = (t & 1) ? hhi1 : hhi0;
        const ushort* hr_lo = (t & 1) ? hlo1 : hlo0;
        ushort* hw_hi = (t & 1) ? hhi0 : hhi1;
        ushort* hw_lo = (t & 1) ? hlo0 : hlo1;
        scan_step<<<256, 256, 0, stream>>>(C, Wih, Whh, bih, bhh, Gbuf,
                                           hr_hi, hr_lo, hw_hi, hw_lo,
                                           out, t, (t == S_ - 1) ? 1 : 0);
    }
}

// Round 4
// 1461.962 us; speedup vs baseline: 1.7028x; 1.7028x over previous
//
// EpisodicMemory: fp32 inputs/output.
//   prep_w    : one-shot fp32->bf16 conversion of fc1_w, W_ih, W_hh into ws (kills
//               the per-step per-block conversion VALU that dominated R3's scan).
//   g_kernel  : per-b block. C chunk loaded ONCE into registers, reused across the
//               4 feature segments (R3 re-read C 4x -> 278MB fetch). fc1w staged as
//               pure uint4 bf16 copies. feat@fc1w^T via 16x16x32 bf16 MFMA.
//   scan_step : one launch per t. gates = C_t@Wih^T + h@Whh^T. C,W single bf16
//               (stationary-noise analysis: adds ~1e-3, validated by R3 absmax);
//               h carried bf16 hi+lo (exact-ish recurrence, no requant random walk),
//               double-buffered. 9 MFMAs per fragment-pair (was 18), LDS 55KB.
#include <hip/hip_runtime.h>
#include <hip/hip_bf16.h>

#define H_ 512
#define SH_ 120
#define B_ 1024
#define S_ 64

typedef __bf16 bf16x8 __attribute__((ext_vector_type(8)));
typedef float floatx4 __attribute__((ext_vector_type(4)));

__device__ __forceinline__ float bf2f(ushort u) {
    union { unsigned int i; float f; } v; v.i = ((unsigned int)u) << 16; return v.f;
}
__device__ __forceinline__ ushort f2bf(float f) {
    union { float f; unsigned int i; } v; v.f = f;
    unsigned int x = v.i;
    unsigned int r = (x + 0x7fffu + ((x >> 16) & 1u)) >> 16;  // RNE
    return (ushort)r;
}

// ---------------------------------------------------------------------------
// prep_w: one-shot fp32 -> bf16 of the three weight matrices.
// ---------------------------------------------------------------------------
__global__ __launch_bounds__(256) void prep_w(
    const float* __restrict__ fc1w, ushort* __restrict__ fc1wb,
    const float* __restrict__ Wih,  ushort* __restrict__ Wihb,
    const float* __restrict__ Whh,  ushort* __restrict__ Whhb)
{
    const int stride = gridDim.x * blockDim.x;
    const int tid = blockIdx.x * blockDim.x + threadIdx.x;
    for (int i = tid; i < 61440; i += stride) {            // 120*2048/4
        const float4 v = ((const float4*)fc1w)[i];
        ushort4 o; o.x = f2bf(v.x); o.y = f2bf(v.y); o.z = f2bf(v.z); o.w = f2bf(v.w);
        ((ushort4*)fc1wb)[i] = o;
    }
    for (int i = tid; i < 196608; i += stride) {           // 1536*512/4
        const float4 v = ((const float4*)Wih)[i];
        ushort4 o; o.x = f2bf(v.x); o.y = f2bf(v.y); o.z = f2bf(v.z); o.w = f2bf(v.w);
        ((ushort4*)Wihb)[i] = o;
    }
    for (int i = tid; i < 196608; i += stride) {
        const float4 v = ((const float4*)Whh)[i];
        ushort4 o; o.x = f2bf(v.x); o.y = f2bf(v.y); o.z = f2bf(v.z); o.w = f2bf(v.w);
        ((ushort4*)Whhb)[i] = o;
    }
}

// ---------------------------------------------------------------------------
// G kernel: one block per b. Computes G[b, s] for s=0..63.
// C chunk held in registers across the 4 feature segments.
// ---------------------------------------------------------------------------
__global__ __launch_bounds__(256) void g_kernel(
    const float* __restrict__ C, const float* __restrict__ Q,
    const float* __restrict__ M, const ushort* __restrict__ fc1wb,
    const float* __restrict__ fc1b, const float* __restrict__ fc2w,
    const float* __restrict__ fc2b, float* __restrict__ G)
{
    __shared__ float qrow[H_];
    __shared__ float mrow[H_];
    __shared__ __align__(16) ushort featT[64 * 72];   // 64 s-rows x 64 k (stride 72)
    __shared__ __align__(16) ushort wT[128 * 72];     // 128 n-rows x 64 k (rows>=120 zero)
    __shared__ float h1s[64 * 132];                   // 64 x 128 fp32 (stride 132)

    const int b = blockIdx.x;
    const int t = threadIdx.x;
    for (int i = t; i < H_; i += 256) { qrow[i] = Q[(size_t)b * H_ + i]; mrow[i] = M[(size_t)b * H_ + i]; }

    const int wrow = t >> 1;
    const int wc0  = (t & 1) * 32;
    if (wrow >= SH_) {              // zero-fill dead wT rows once
        uint4* dst = (uint4*)&wT[wrow * 72 + wc0];
        const uint4 z = {0u, 0u, 0u, 0u};
        dst[0] = z; dst[1] = z; dst[2] = z; dst[3] = z;
    }
    __syncthreads();

    const int lane = t & 63;
    const int wv   = t >> 6;
    const int quad = lane >> 4;
    const int l15  = lane & 15;
    const int arow = wv * 16 + l15;
    const int s    = t >> 2;
    const int c0   = (t & 3) * 16;

    floatx4 acc[8];
#pragma unroll
    for (int i = 0; i < 8; ++i) acc[i] = (floatx4){0.f, 0.f, 0.f, 0.f};

    for (int hc = 0; hc < H_; hc += 64) {
        // --- C chunk into registers (once per hc, reused for 4 segs) ---
        float cr[16];
        {
            const float4* csrc = (const float4*)(C + ((size_t)b * S_ + s) * H_ + hc + c0);
            *(float4*)&cr[0]  = csrc[0];
            *(float4*)&cr[4]  = csrc[1];
            *(float4*)&cr[8]  = csrc[2];
            *(float4*)&cr[12] = csrc[3];
        }
#pragma unroll
        for (int seg = 0; seg < 4; ++seg) {
            // --- feat tile from registers ---
#pragma unroll
            for (int u = 0; u < 16; ++u) {
                const int kk = c0 + u;
                const float c = cr[u];
                const float o = (seg == 0 || seg == 2) ? qrow[hc + kk] : mrow[hc + kk];
                const float v = (seg < 2) ? c * o : fabsf(c - o);
                featT[s * 72 + kk] = f2bf(v);
            }
            // --- fc1w tile: pure uint4 copies from pre-converted bf16 ---
            if (wrow < SH_) {
                const uint4* src = (const uint4*)(fc1wb + (size_t)wrow * (4 * H_) + seg * H_ + hc + wc0);
                uint4* dst = (uint4*)&wT[wrow * 72 + wc0];
                dst[0] = src[0]; dst[1] = src[1]; dst[2] = src[2]; dst[3] = src[3];
            }
            __syncthreads();
#pragma unroll
            for (int ks = 0; ks < 64; ks += 32) {
                const int ao = ks + quad * 8;
                const bf16x8 af = *(const bf16x8*)&featT[arow * 72 + ao];
#pragma unroll
                for (int nt = 0; nt < 8; ++nt) {
                    const bf16x8 bfr = *(const bf16x8*)&wT[(nt * 16 + l15) * 72 + ao];
                    acc[nt] = __builtin_amdgcn_mfma_f32_16x16x32_bf16(af, bfr, acc[nt], 0, 0, 0);
                }
            }
            __syncthreads();
        }
    }

    // --- epilogue: h1 = tanh(acc + fc1_b) into LDS ---
#pragma unroll
    for (int nt = 0; nt < 8; ++nt) {
        const int col = nt * 16 + l15;
        const float bias = (col < SH_) ? fc1b[col] : 0.f;
#pragma unroll
        for (int r = 0; r < 4; ++r) {
            const int row = wv * 16 + quad * 4 + r;
            h1s[row * 132 + col] = (col < SH_) ? tanhf(acc[nt][r] + bias) : 0.f;
        }
    }
    __syncthreads();
    // --- fc2 + sigmoid: 4 threads per s-row ---
    {
        const int part = t & 3;
        float sum = 0.f;
        for (int k = part; k < SH_; k += 4) sum += h1s[s * 132 + k] * fc2w[k];
        sum += __shfl_xor(sum, 1);
        sum += __shfl_xor(sum, 2);
        if (part == 0) {
            const float logit = sum + fc2b[0];
            G[(size_t)b * S_ + s] = 1.f / (1.f + expf(-logit));
        }
    }
}

// ---------------------------------------------------------------------------
// scan_step: grid = 256 blocks = 16 j-tiles x 16 b-tiles. Block computes h_new
// for its 64-batch x 32-hidden tile at step tstep. C single bf16 (on the fly),
// W single bf16 (pre-converted), h recurrent state bf16 hi+lo, double-buffered.
// ---------------------------------------------------------------------------
__global__ __launch_bounds__(256) void scan_step(
    const float* __restrict__ C, const ushort* __restrict__ Wihb,
    const ushort* __restrict__ Whhb, const float* __restrict__ bih,
    const float* __restrict__ bhh, const float* __restrict__ G,
    const ushort* __restrict__ hhi_r, const ushort* __restrict__ hlo_r,
    ushort* __restrict__ hhi_w, ushort* __restrict__ hlo_w,
    float* __restrict__ out, int tstep, int last)
{
    __shared__ __align__(16) ushort As[3 * 4608];  // c | h_hi | h_lo : 64 rows x 64 k (stride 72)
    __shared__ __align__(16) ushort Bs[2 * 6912];  // Wih | Whh : 96 rows x 64 k (stride 72)

    const int bx = blockIdx.x;
    const int jt = bx & 15;
    const int bt = bx >> 4;
    const int jb = jt * 32;
    const int bb = bt * 64;
    const int t  = threadIdx.x;
    const int lane = t & 63;
    const int wv   = t >> 6;
    const int quad = lane >> 4;
    const int l15  = lane & 15;
    const int arow = wv * 16 + l15;
    const int crow = t >> 2;
    const int cc0  = (t & 3) * 16;

    floatx4 acc_r[2], acc_z[2], acc_xn[2], acc_hn[2];
#pragma unroll
    for (int i = 0; i < 2; ++i) {
        acc_r[i] = (floatx4){0.f,0.f,0.f,0.f}; acc_z[i]  = (floatx4){0.f,0.f,0.f,0.f};
        acc_xn[i]= (floatx4){0.f,0.f,0.f,0.f}; acc_hn[i] = (floatx4){0.f,0.f,0.f,0.f};
    }

    for (int kc = 0; kc < H_; kc += 64) {
        // --- C tile: fp32 -> single bf16 on the fly ---
        {
            const float4* src = (const float4*)(C + ((size_t)(bb + crow) * S_ + tstep) * H_ + kc + cc0);
            float cr[16];
            *(float4*)&cr[0]  = src[0];
            *(float4*)&cr[4]  = src[1];
            *(float4*)&cr[8]  = src[2];
            *(float4*)&cr[12] = src[3];
            __align__(16) ushort cb[16];
#pragma unroll
            for (int u = 0; u < 16; ++u) cb[u] = f2bf(cr[u]);
            uint4* d = (uint4*)&As[crow * 72 + cc0];
            d[0] = ((uint4*)cb)[0]; d[1] = ((uint4*)cb)[1];
        }
        // --- h hi/lo tiles: pure uint4 copies, 2 tiles x 512 uint4, 4 per thread ---
#pragma unroll
        for (int i = 0; i < 4; ++i) {
            const int gid  = i * 256 + t;
            const int tile = gid >> 9;        // 0: h_hi, 1: h_lo
            const int rem  = gid & 511;
            const int row  = rem >> 3;
            const int grp  = rem & 7;
            const ushort* src = (tile ? hlo_r : hhi_r) + (size_t)(bb + row) * H_ + kc + grp * 8;
            *(uint4*)&As[(1 + tile) * 4608 + row * 72 + grp * 8] = *(const uint4*)src;
        }
        // --- W tiles: pure uint4 copies from pre-converted bf16, 6 per thread ---
#pragma unroll
        for (int i = 0; i < 6; ++i) {
            const int gid = i * 256 + t;
            const int mat = (gid >= 768) ? 1 : 0;
            const int rem = gid - mat * 768;
            const int row = rem >> 3;         // 0..95
            const int grp = rem & 7;
            const int gate = row >> 5;
            const int jj   = row & 31;
            const int grow = gate * H_ + jb + jj;
            const ushort* src = (mat ? Whhb : Wihb) + (size_t)grow * H_ + kc + grp * 8;
            *(uint4*)&Bs[mat * 6912 + row * 72 + grp * 8] = *(const uint4*)src;
        }
        __syncthreads();
#pragma unroll
        for (int ks = 0; ks < 64; ks += 32) {
            const int ao = ks + quad * 8;
            const bf16x8 a_c  = *(const bf16x8*)&As[0 * 4608 + arow * 72 + ao];
            const bf16x8 a_hh = *(const bf16x8*)&As[1 * 4608 + arow * 72 + ao];
            const bf16x8 a_hl = *(const bf16x8*)&As[2 * 4608 + arow * 72 + ao];
#pragma unroll
            for (int nt = 0; nt < 2; ++nt) {
                const int jj = nt * 16 + l15;
                const bf16x8 ih_r = *(const bf16x8*)&Bs[0 * 6912 + (0 * 32 + jj) * 72 + ao];
                const bf16x8 ih_z = *(const bf16x8*)&Bs[0 * 6912 + (1 * 32 + jj) * 72 + ao];
                const bf16x8 ih_n = *(const bf16x8*)&Bs[0 * 6912 + (2 * 32 + jj) * 72 + ao];
                const bf16x8 hh_r = *(const bf16x8*)&Bs[1 * 6912 + (0 * 32 + jj) * 72 + ao];
                const bf16x8 hh_z = *(const bf16x8*)&Bs[1 * 6912 + (1 * 32 + jj) * 72 + ao];
                const bf16x8 hh_n = *(const bf16x8*)&Bs[1 * 6912 + (2 * 32 + jj) * 72 + ao];
                acc_r[nt]  = __builtin_amdgcn_mfma_f32_16x16x32_bf16(a_c,  ih_r, acc_r[nt],  0, 0, 0);
                acc_r[nt]  = __builtin_amdgcn_mfma_f32_16x16x32_bf16(a_hh, hh_r, acc_r[nt],  0, 0, 0);
                acc_r[nt]  = __builtin_amdgcn_mfma_f32_16x16x32_bf16(a_hl, hh_r, acc_r[nt],  0, 0, 0);
                acc_z[nt]  = __builtin_amdgcn_mfma_f32_16x16x32_bf16(a_c,  ih_z, acc_z[nt],  0, 0, 0);
                acc_z[nt]  = __builtin_amdgcn_mfma_f32_16x16x32_bf16(a_hh, hh_z, acc_z[nt],  0, 0, 0);
                acc_z[nt]  = __builtin_amdgcn_mfma_f32_16x16x32_bf16(a_hl, hh_z, acc_z[nt],  0, 0, 0);
                acc_xn[nt] = __builtin_amdgcn_mfma_f32_16x16x32_bf16(a_c,  ih_n, acc_xn[nt], 0, 0, 0);
                acc_hn[nt] = __builtin_amdgcn_mfma_f32_16x16x32_bf16(a_hh, hh_n, acc_hn[nt], 0, 0, 0);
                acc_hn[nt] = __builtin_amdgcn_mfma_f32_16x16x32_bf16(a_hl, hh_n, acc_hn[nt], 0, 0, 0);
            }
        }
        __syncthreads();
    }

    // --- epilogue: gates -> h_new ---
#pragma unroll
    for (int nt = 0; nt < 2; ++nt) {
        const int j = jb + nt * 16 + l15;
        const float br  = bih[j]          + bhh[j];
        const float bz  = bih[H_ + j]     + bhh[H_ + j];
        const float bxn = bih[2 * H_ + j];
        const float bhn = bhh[2 * H_ + j];
#pragma unroll
        for (int r4 = 0; r4 < 4; ++r4) {
            const int b = bb + wv * 16 + quad * 4 + r4;
            const size_t idx = (size_t)b * H_ + j;
            const float hold = bf2f(hhi_r[idx]) + bf2f(hlo_r[idx]);  // read-buffer: no race
            const float g = G[(size_t)b * S_ + tstep];
            const float rg = 1.f / (1.f + expf(-(acc_r[nt][r4] + br)));
            const float zg = 1.f / (1.f + expf(-(acc_z[nt][r4] + bz)));
            const float ng = tanhf(acc_xn[nt][r4] + bxn + rg * (acc_hn[nt][r4] + bhn));
            const float hgru = (1.f - zg) * ng + zg * hold;
            const float hnew = g * hgru + (1.f - g) * hold;
            const ushort hb = f2bf(hnew);
            hhi_w[idx] = hb;
            hlo_w[idx] = f2bf(hnew - bf2f(hb));
            if (last) out[idx] = hnew;
        }
    }
}

extern "C" void kernel_launch(void* const* d_in, const int* in_sizes, int n_in,
                              void* d_out, int out_size, void* d_ws, size_t ws_size,
                              hipStream_t stream) {
    (void)in_sizes; (void)n_in; (void)out_size; (void)ws_size;
    const float* C    = (const float*)d_in[0];
    const float* Q    = (const float*)d_in[1];
    const float* M    = (const float*)d_in[2];
    const float* fc1w = (const float*)d_in[3];
    const float* fc1b = (const float*)d_in[4];
    const float* fc2w = (const float*)d_in[5];
    const float* fc2b = (const float*)d_in[6];
    const float* Wih  = (const float*)d_in[7];
    const float* Whh  = (const float*)d_in[8];
    const float* bih  = (const float*)d_in[9];
    const float* bhh  = (const float*)d_in[10];
    float* out = (float*)d_out;

    char* ws = (char*)d_ws;
    float*  Gbuf  = (float*)ws;                          // 256 KB
    ushort* hhi0  = (ushort*)(ws + 262144);              // 1 MB
    ushort* hlo0  = (ushort*)(ws + 262144 + 1048576);    // 1 MB
    ushort* hhi1  = (ushort*)(ws + 262144 + 2097152);    // 1 MB
    ushort* hlo1  = (ushort*)(ws + 262144 + 3145728);    // 1 MB
    ushort* fc1wb = (ushort*)(ws + 4456448);             // 480 KB
    ushort* Wihb  = (ushort*)(ws + 4947968);             // 1.5 MB
    ushort* Whhb  = (ushort*)(ws + 6520832);             // 1.5 MB (ends ~7.72 MB)

    // h0 = 0: zero buffer 0 (hhi0+hlo0 contiguous; buffer 1 fully written at t=0)
    hipMemsetAsync(hhi0, 0, 2097152, stream);

    prep_w<<<256, 256, 0, stream>>>(fc1w, fc1wb, Wih, Wihb, Whh, Whhb);
    g_kernel<<<B_, 256, 0, stream>>>(C, Q, M, fc1wb, fc1b, fc2w, fc2b, Gbuf);
    for (int t = 0; t < S_; ++t) {
        const ushort* hr_hi = (t & 1) ? hhi1 : hhi0;
        const ushort* hr_lo = (t & 1) ? hlo1 : hlo0;
        ushort* hw_hi = (t & 1) ? hhi0 : hhi1;
        ushort* hw_lo = (t & 1) ? hlo0 : hlo1;
        scan_step<<<256, 256, 0, stream>>>(C, Wihb, Whhb, bih, bhh, Gbuf,
                                           hr_hi, hr_lo, hw_hi, hw_lo,
                                           out, t, (t == S_ - 1) ? 1 : 0);
    }
}